// Round 8
// baseline (1047.693 us; speedup 1.0000x reference)
//
#include <hip/hip_runtime.h>
#include <stdint.h>

#define IN_DIM 8192
#define OUT_DIM 4096
#define NNZ 1638400
#define BATCH 4096

typedef __bf16 bf16x8 __attribute__((ext_vector_type(8)));
typedef float f32x4 __attribute__((ext_vector_type(4)));

// ---- helpers ----------------------------------------------------------------

__device__ __forceinline__ unsigned short f2bf(float f) {
  union { float f; unsigned int u; } v; v.f = f;
  unsigned int u = v.u;
  unsigned int r = (u + 0x7FFFu + ((u >> 16) & 1u)) >> 16;  // RNE
  return (unsigned short)r;
}

__device__ __forceinline__ float bf2f(unsigned short b) {
  union { unsigned int u; float f; } v;
  v.u = (unsigned int)b << 16;
  return v.f;
}

__device__ __forceinline__ void convert_body(int i, const float* __restrict__ src,
                                             unsigned short* __restrict__ dst) {
  const float4* s = (const float4*)src;
  float4 a = s[2 * i];
  float4 b = s[2 * i + 1];
  union { unsigned short us[8]; uint4 v; } o;
  o.us[0] = f2bf(a.x); o.us[1] = f2bf(a.y); o.us[2] = f2bf(a.z); o.us[3] = f2bf(a.w);
  o.us[4] = f2bf(b.x); o.us[5] = f2bf(b.y); o.us[6] = f2bf(b.z); o.us[7] = f2bf(b.w);
  ((uint4*)dst)[i] = o.v;
}

// ---- kernel 1: zero W_bf16 + convert x (unchanged since R0) -----------------

#define PREP_BLOCKS ((IN_DIM * OUT_DIM) / 8 / 256)  // 16384

__global__ void prep_kernel(uint4* __restrict__ W_zero,
                            const float* __restrict__ x,
                            unsigned short* __restrict__ x_bf16) {
  int i = blockIdx.x * 256 + threadIdx.x;
  W_zero[i] = make_uint4(0, 0, 0, 0);
  convert_body(i, x, x_bf16);
}

// ---- kernel 2: scatter-add into bf16 W via 32-bit CAS (unchanged) -----------

__device__ __forceinline__ void scat1(int c, int r, float w,
                                      unsigned int* __restrict__ W) {
  size_t e = (size_t)c * IN_DIM + r;     // element index in W^T [OUT][IN]
  unsigned int* p = W + (e >> 1);
  const bool hi = (e & 1);
  unsigned int cur = *p;                 // seed (CAS corrects staleness)
  unsigned int assumed;
  do {
    assumed = cur;
    unsigned short h = hi ? (unsigned short)(assumed >> 16)
                          : (unsigned short)(assumed & 0xFFFFu);
    unsigned short nb = f2bf(bf2f(h) + w);
    unsigned int nw = hi ? ((assumed & 0x0000FFFFu) | ((unsigned int)nb << 16))
                         : ((assumed & 0xFFFF0000u) | (unsigned int)nb);
    cur = atomicCAS(p, assumed, nw);
  } while (cur != assumed);
}

#define SCAT_BLOCKS (NNZ / 4 / 256)  // 1600

__global__ void scatter_kernel(const int4* __restrict__ ri4,
                               const int4* __restrict__ ci4,
                               const float4* __restrict__ w4,
                               unsigned int* __restrict__ W) {
  int i = blockIdx.x * 256 + threadIdx.x;
  int4 r = ri4[i];
  int4 c = ci4[i];
  float4 w = w4[i];
  scat1(c.x, r.x, w.x, W);
  scat1(c.y, r.y, w.y, W);
  scat1(c.z, r.z, w.z, W);
  scat1(c.w, r.w, w.w, W);
}

// ---- kernel 3: bf16 GEMM, 256x256, 8 waves, REG-STAGED double buffer --------
// R5 structure (barrier-light, XCD region swizzle, same fragment/epilogue
// layout) with ONE change: staging via global_load_dwordx4 -> VGPR ->
// ds_write_b128 instead of global_load_lds. Theory: the async DMA path caps
// CU ingest at ~16 B/cyc (64 x 1KB wave-instr -> 4096 cyc/tile = measured
// tile time); reg-staging (HK-style) sustains ~28 B/cyc.
// Per tile t: [buf visible] frag ds_reads + 64 MFMA from buf; then commit
// regs (tile t+1 data, loaded one full tile ago -> compiler's counted vmcnt
// ~free) to nbuf via 8 ds_write_b128 (linear dest, conflict-free); reissue
// loads for tile t+2 into the same regs (in-order issue => WAR safe);
// lgkmcnt(0); s_barrier. One barrier per tile.
// nbuf deadness: all waves' reads of nbuf (tile t-1 frags) were consumed by
// their MFMAs before they issued their own ds_writes ahead of the previous
// barrier -> overwrite safe.

#define TBM 256
#define TBN 256
#define TBK 64
#define NKT (IN_DIM / TBK)  // 128

__global__ __launch_bounds__(512, 2) void gemm_kernel(
    const unsigned short* __restrict__ A,   // [BATCH][IN_DIM] bf16 bits
    const unsigned short* __restrict__ Bt,  // [OUT_DIM][IN_DIM] bf16 bits
    const float* __restrict__ bias,         // [OUT_DIM]
    float* __restrict__ C) {                // [BATCH][OUT_DIM] fp32
  extern __shared__ __align__(16) unsigned short lds[];  // 131072 B

  const int tid = threadIdx.x;

  // XCD-region swizzle: 8m x 4n block region per XCD (R5, kept).
  const int bid = blockIdx.x;
  const int xcd = bid & 7;
  const int jb = bid >> 3;
  const int m0 = ((xcd & 1) * 8 + (jb & 7)) * TBM;
  const int n0 = ((xcd >> 1) * 4 + (jb >> 3)) * TBN;

  const int wid = tid >> 6;
  const int lane = tid & 63;
  const int wm = wid >> 2;       // 0..1
  const int wn = wid & 3;        // 0..3
  const int quad = lane >> 4;
  const int lm = lane & 15;
  const int xorv = lm & 7;

  const unsigned short* Ab = A + (size_t)m0 * IN_DIM;
  const unsigned short* Bb = Bt + (size_t)n0 * IN_DIM;

  // staging geometry: tile = 256 rows x 8 segs of 16B; 512 thr -> 4 rounds.
  // Global side pre-swizzled; LDS dest linear (conflict-free b128 writes) ->
  // identical final layout to the old DMA path; read side unchanged.
  int soff[4], ldst[4];
#pragma unroll
  for (int c = 0; c < 4; ++c) {
    const int t2 = c * 512 + tid;
    const int srow = t2 >> 3;
    const int sgs = (t2 & 7) ^ (srow & 7);    // stage-side swizzle
    soff[c] = srow * IN_DIM + sgs * 8;
    ldst[c] = t2 * 16;                         // LDS byte offset (linear dest)
  }

  f32x4 acc[8][4] = {};

  uint4 sA[4], sB[4];  // staging registers (32 VGPRs)

#define LOADG(kt_)                                                          \
  do {                                                                      \
    const int k0_ = (kt_)*TBK;                                              \
    _Pragma("unroll") for (int c = 0; c < 4; ++c) {                         \
      sA[c] = *(const uint4*)(Ab + (size_t)soff[c] + k0_);                  \
      sB[c] = *(const uint4*)(Bb + (size_t)soff[c] + k0_);                  \
    }                                                                       \
  } while (0)

#define COMMIT(b_)                                                          \
  do {                                                                      \
    char* la_ = (char*)lds + (b_)*65536;                                    \
    _Pragma("unroll") for (int c = 0; c < 4; ++c) {                         \
      *(uint4*)(la_ + ldst[c]) = sA[c];                                     \
      *(uint4*)(la_ + 32768 + ldst[c]) = sB[c];                             \
    }                                                                       \
  } while (0)

  // prologue: tile 0 -> regs -> buf0; start tile 1 loads; make buf0 visible.
  LOADG(0);
  COMMIT(0);
  LOADG(1);
  asm volatile("s_waitcnt lgkmcnt(0)" ::: "memory");
  __builtin_amdgcn_sched_barrier(0);
  __builtin_amdgcn_s_barrier();
  __builtin_amdgcn_sched_barrier(0);

  for (int kt = 0; kt < NKT; ++kt) {
    const int buf = kt & 1;
    const int nbuf = buf ^ 1;
    const int kt2 = (kt + 2) & (NKT - 1);  // wraps at end: dummy loads

    const unsigned short* lA = lds + buf * 32768;  // elements (64 KiB/buf)
    const unsigned short* lB = lA + 16384;

    // B fragments for the whole K-tile (8 x ds_read_b128, held in regs)
    bf16x8 bfr[4][2];
#pragma unroll
    for (int j2 = 0; j2 < 4; ++j2) {
      const int row = wn * 64 + j2 * 16 + lm;
#pragma unroll
      for (int ss = 0; ss < 2; ++ss) {
        const int p = ((ss << 2) | quad) ^ xorv;   // read-side inverse swizzle
        bfr[j2][ss] = *(const bf16x8*)(lB + row * TBK + p * 8);
      }
    }

#pragma unroll
    for (int q = 0; q < 4; ++q) {
      bf16x8 af[2][2];
#pragma unroll
      for (int i = 0; i < 2; ++i) {
        const int row = wm * 128 + (q * 2 + i) * 16 + lm;
#pragma unroll
        for (int ss = 0; ss < 2; ++ss) {
          const int p = ((ss << 2) | quad) ^ xorv;
          af[i][ss] = *(const bf16x8*)(lA + row * TBK + p * 8);
        }
      }
      __builtin_amdgcn_s_setprio(1);
#pragma unroll
      for (int i = 0; i < 2; ++i)
#pragma unroll
        for (int j2 = 0; j2 < 4; ++j2)
#pragma unroll
          for (int ss = 0; ss < 2; ++ss)
            acc[q * 2 + i][j2] = __builtin_amdgcn_mfma_f32_16x16x32_bf16(
                af[i][ss], bfr[j2][ss], acc[q * 2 + i][j2], 0, 0, 0);
      __builtin_amdgcn_s_setprio(0);
    }

    // commit tile kt+1 (regs, loaded one tile ago) into the dead buffer;
    // compiler inserts the counted vmcnt before these uses.
    COMMIT(nbuf);
    // reissue loads for tile kt+2 into the now-free regs (in-order => safe).
    LOADG(kt2);
    asm volatile("s_waitcnt lgkmcnt(0)" ::: "memory");
    __builtin_amdgcn_sched_barrier(0);
    __builtin_amdgcn_s_barrier();
    __builtin_amdgcn_sched_barrier(0);
  }
#undef COMMIT
#undef LOADG

  // Epilogue: C/D layout col = lane&15, row = quad*4 + reg  [m89-verified]
  const int ccol0 = n0 + wn * 64 + lm;
  const int crow0 = m0 + wm * 128;
#pragma unroll
  for (int j2 = 0; j2 < 4; ++j2) {
    const int col = ccol0 + j2 * 16;
    const float bv = bias[col];
#pragma unroll
    for (int i = 0; i < 8; ++i) {
#pragma unroll
      for (int v = 0; v < 4; ++v) {
        const int row = crow0 + i * 16 + quad * 4 + v;
        C[(size_t)row * OUT_DIM + col] = acc[i][j2][v] + bv;
      }
    }
  }
}

// ---- launch -----------------------------------------------------------------

extern "C" void kernel_launch(void* const* d_in, const int* in_sizes, int n_in,
                              void* d_out, int out_size, void* d_ws, size_t ws_size,
                              hipStream_t stream) {
  const float* x = (const float*)d_in[0];       // [4096][8192] fp32
  const int* row_idx = (const int*)d_in[1];     // [NNZ] int32
  const int* col_idx = (const int*)d_in[2];     // [NNZ] int32
  const float* weights = (const float*)d_in[3]; // [NNZ] fp32
  const float* bias = (const float*)d_in[4];    // [4096] fp32
  float* out = (float*)d_out;                   // [4096][4096] fp32

  // ws layout: W_bf16 [0,64M), x_bf16 [64M,128M).
  const size_t W_BF16_BYTES = (size_t)IN_DIM * OUT_DIM * 2;  // 64 MiB
  unsigned short* W_bf16 = (unsigned short*)d_ws;
  unsigned short* x_bf16 = (unsigned short*)((char*)d_ws + W_BF16_BYTES);

  static bool attr_set = false;
  if (!attr_set) {
    (void)hipFuncSetAttribute((const void*)gemm_kernel,
                              hipFuncAttributeMaxDynamicSharedMemorySize,
                              131072);
    attr_set = true;
  }

  // 1. zero W_bf16 + convert x -> bf16
  prep_kernel<<<PREP_BLOCKS, 256, 0, stream>>>((uint4*)W_bf16, x, x_bf16);

  // 2. scatter-add weights directly into bf16 W^T (CAS)
  scatter_kernel<<<SCAT_BLOCKS, 256, 0, stream>>>(
      (const int4*)row_idx, (const int4*)col_idx, (const float4*)weights,
      (unsigned int*)W_bf16);

  // 3. GEMM + bias (256^2 tile, 8 waves, XCD-region-swizzled grid of 256)
  gemm_kernel<<<dim3(256), dim3(512), 131072, stream>>>(x_bf16, W_bf16, bias, out);
}

// Round 9
// 519.726 us; speedup vs baseline: 2.0159x; 2.0159x over previous
//
#include <hip/hip_runtime.h>
#include <stdint.h>

#define IN_DIM 8192
#define OUT_DIM 4096
#define NNZ 1638400
#define BATCH 4096

typedef __bf16 bf16x8 __attribute__((ext_vector_type(8)));
typedef float f32x16 __attribute__((ext_vector_type(16)));

// ---- helpers ----------------------------------------------------------------

__device__ __forceinline__ unsigned short f2bf(float f) {
  union { float f; unsigned int u; } v; v.f = f;
  unsigned int u = v.u;
  unsigned int r = (u + 0x7FFFu + ((u >> 16) & 1u)) >> 16;  // RNE
  return (unsigned short)r;
}

__device__ __forceinline__ float bf2f(unsigned short b) {
  union { unsigned int u; float f; } v;
  v.u = (unsigned int)b << 16;
  return v.f;
}

__device__ __forceinline__ void async16(const void* g, void* l) {
  __builtin_amdgcn_global_load_lds(
      (const __attribute__((address_space(1))) unsigned int*)g,
      (__attribute__((address_space(3))) unsigned int*)l,
      16, 0, 0);
}

__device__ __forceinline__ void convert_body(int i, const float* __restrict__ src,
                                             unsigned short* __restrict__ dst) {
  const float4* s = (const float4*)src;
  float4 a = s[2 * i];
  float4 b = s[2 * i + 1];
  union { unsigned short us[8]; uint4 v; } o;
  o.us[0] = f2bf(a.x); o.us[1] = f2bf(a.y); o.us[2] = f2bf(a.z); o.us[3] = f2bf(a.w);
  o.us[4] = f2bf(b.x); o.us[5] = f2bf(b.y); o.us[6] = f2bf(b.z); o.us[7] = f2bf(b.w);
  ((uint4*)dst)[i] = o.v;
}

// ---- kernel 1: zero W_bf16 + convert x (unchanged since R0) -----------------

#define PREP_BLOCKS ((IN_DIM * OUT_DIM) / 8 / 256)  // 16384

__global__ void prep_kernel(uint4* __restrict__ W_zero,
                            const float* __restrict__ x,
                            unsigned short* __restrict__ x_bf16) {
  int i = blockIdx.x * 256 + threadIdx.x;
  W_zero[i] = make_uint4(0, 0, 0, 0);
  convert_body(i, x, x_bf16);
}

// ---- kernel 2: scatter-add into bf16 W via 32-bit CAS (unchanged) -----------

__device__ __forceinline__ void scat1(int c, int r, float w,
                                      unsigned int* __restrict__ W) {
  size_t e = (size_t)c * IN_DIM + r;     // element index in W^T [OUT][IN]
  unsigned int* p = W + (e >> 1);
  const bool hi = (e & 1);
  unsigned int cur = *p;                 // seed (CAS corrects staleness)
  unsigned int assumed;
  do {
    assumed = cur;
    unsigned short h = hi ? (unsigned short)(assumed >> 16)
                          : (unsigned short)(assumed & 0xFFFFu);
    unsigned short nb = f2bf(bf2f(h) + w);
    unsigned int nw = hi ? ((assumed & 0x0000FFFFu) | ((unsigned int)nb << 16))
                         : ((assumed & 0xFFFF0000u) | (unsigned int)nb);
    cur = atomicCAS(p, assumed, nw);
  } while (cur != assumed);
}

#define SCAT_BLOCKS (NNZ / 4 / 256)  // 1600

__global__ void scatter_kernel(const int4* __restrict__ ri4,
                               const int4* __restrict__ ci4,
                               const float4* __restrict__ w4,
                               unsigned int* __restrict__ W) {
  int i = blockIdx.x * 256 + threadIdx.x;
  int4 r = ri4[i];
  int4 c = ci4[i];
  float4 w = w4[i];
  scat1(c.x, r.x, w.x, W);
  scat1(c.y, r.y, w.y, W);
  scat1(c.z, r.z, w.z, W);
  scat1(c.w, r.w, w.w, W);
}

// ---- kernel 3: bf16 GEMM, 256x256, 8 waves, barrier-light, 32x32x16 MFMA ----
// Exactly R5's proven structure (506 us total: DMA staging, XOR swizzle,
// 1 barrier/tile, XCD region swizzle) with ONE change: MFMA shape
// 16x16x32 -> 32x32x16. 32x32 ceiling is 2495 TF vs 2075 (16x16): per-tile
// MFMA wall 2483 -> 2067 cyc, instr count halves (less issue pressure).
// LDS bytes identical. Fragment layouts:
//   A/B operand: lane&31 = row (A-m / B-n), lane>>5 = k-half of the instr's
//     K=16; lane holds 8 consecutive k. Per K-tile: instr s covers
//     k in [16s,16s+16) -> lane's 16B chunk index = 2s + (lane>>5).
//   C/D [m74/m101-verified]: col = lane&31, row = (reg&3)+8*(reg>>2)
//     +4*(lane>>5), reg in [0,16).
// Swizzle: chunk p stored at p^(row&7); all row bases are multiples of 8 so
// row&7 = (lane&31)&7 on both stage and read sides.

#define TBM 256
#define TBN 256
#define TBK 64
#define NKT (IN_DIM / TBK)  // 128

__global__ __launch_bounds__(512, 2) void gemm_kernel(
    const unsigned short* __restrict__ A,   // [BATCH][IN_DIM] bf16 bits
    const unsigned short* __restrict__ Bt,  // [OUT_DIM][IN_DIM] bf16 bits
    const float* __restrict__ bias,         // [OUT_DIM]
    float* __restrict__ C) {                // [BATCH][OUT_DIM] fp32
  extern __shared__ __align__(16) unsigned short lds[];  // 131072 B

  const int tid = threadIdx.x;

  // XCD-region swizzle: 8m x 4n block region per XCD (R5, kept).
  const int bid = blockIdx.x;
  const int xcd = bid & 7;
  const int jb = bid >> 3;
  const int m0 = ((xcd & 1) * 8 + (jb & 7)) * TBM;
  const int n0 = ((xcd >> 1) * 4 + (jb >> 3)) * TBN;

  const int wid = tid >> 6;
  const int lane = tid & 63;
  const int wm = wid >> 2;       // 0..1
  const int wn = wid & 3;        // 0..3
  const int l31 = lane & 31;
  const int hi = lane >> 5;      // k-half selector
  const int xr = l31 & 7;        // row&7 for swizzle (row bases are 8-aligned)

  const unsigned short* Ab = A + (size_t)m0 * IN_DIM;
  const unsigned short* Bb = Bt + (size_t)n0 * IN_DIM;

  // staging geometry: tile = 256 rows x 8 segs of 16B; 512 thr -> 4 rounds.
  int soff[4], ldst[4];
#pragma unroll
  for (int c = 0; c < 4; ++c) {
    const int t2 = c * 512 + tid;
    const int srow = t2 >> 3;
    const int sgs = (t2 & 7) ^ (srow & 7);    // stage-side swizzle
    soff[c] = srow * IN_DIM + sgs * 8;
    ldst[c] = t2 * 16;                         // LDS byte offset (linear dest)
  }

  f32x16 acc[4][2] = {};  // 4 m-tiles x 2 n-tiles of 32x32, 16 f32 each

#define STAGE(kt_, b_, c_)                                                  \
  do {                                                                      \
    const int k0_ = (kt_)*TBK;                                              \
    char* la_ = (char*)lds + (b_)*65536;                                    \
    async16(Ab + (size_t)soff[c_] + k0_, la_ + ldst[c_]);                   \
    async16(Bb + (size_t)soff[c_] + k0_, la_ + 32768 + ldst[c_]);           \
  } while (0)

  // prologue: stage K-tile 0 fully into buf 0 (8 loads/thread)
#pragma unroll
  for (int c = 0; c < 4; ++c) STAGE(0, 0, c);

  for (int kt = 0; kt < NKT; ++kt) {
    const int buf = kt & 1;
    const int nbuf = buf ^ 1;
    const int ktn = (kt + 1) & (NKT - 1);  // wraps at end: dummy reload

    // (a) own loads of THIS tile drained (aged one full tile)...
    asm volatile("s_waitcnt vmcnt(0)" ::: "memory");
    __builtin_amdgcn_sched_barrier(0);
    // ...then cross-wave visibility + nbuf-read completion fence.
    __builtin_amdgcn_s_barrier();
    __builtin_amdgcn_sched_barrier(0);

    // (b) burst-stage tile kt+1 into the (now provably dead) buffer.
#pragma unroll
    for (int c = 0; c < 4; ++c) STAGE(ktn, nbuf, c);

    const unsigned short* lA = lds + buf * 32768;  // elements (64 KiB/buf)
    const unsigned short* lB = lA + 16384;

    // B fragments for the whole K-tile (8 x ds_read_b128, held in regs)
    bf16x8 bfr[2][4];
#pragma unroll
    for (int j2 = 0; j2 < 2; ++j2) {
      const int row = wn * 64 + j2 * 32 + l31;
#pragma unroll
      for (int s = 0; s < 4; ++s) {
        const int p = ((s << 1) | hi) ^ xr;       // read-side inverse swizzle
        bfr[j2][s] = *(const bf16x8*)(lB + row * TBK + p * 8);
      }
    }

#pragma unroll
    for (int i = 0; i < 4; ++i) {
      bf16x8 af[4];
      const int row = wm * 128 + i * 32 + l31;
#pragma unroll
      for (int s = 0; s < 4; ++s) {
        const int p = ((s << 1) | hi) ^ xr;
        af[s] = *(const bf16x8*)(lA + row * TBK + p * 8);
      }
      __builtin_amdgcn_s_setprio(1);
#pragma unroll
      for (int j2 = 0; j2 < 2; ++j2)
#pragma unroll
        for (int s = 0; s < 4; ++s)
          acc[i][j2] = __builtin_amdgcn_mfma_f32_32x32x16_bf16(
              af[s], bfr[j2][s], acc[i][j2], 0, 0, 0);
      __builtin_amdgcn_s_setprio(0);
    }
  }
#undef STAGE

  // retire the dummy tail loads before LDS deallocation / endpgm.
  asm volatile("s_waitcnt vmcnt(0)" ::: "memory");

  // Epilogue: C/D layout col = lane&31, row = (reg&3)+8*(reg>>2)+4*hi
  // [m74/m101-verified]
  const int ccol0 = n0 + wn * 64 + l31;
  const int crow0 = m0 + wm * 128 + 4 * hi;
#pragma unroll
  for (int j2 = 0; j2 < 2; ++j2) {
    const int col = ccol0 + j2 * 32;
    const float bv = bias[col];
#pragma unroll
    for (int i = 0; i < 4; ++i) {
#pragma unroll
      for (int r = 0; r < 16; ++r) {
        const int row = crow0 + i * 32 + (r & 3) + 8 * (r >> 2);
        C[(size_t)row * OUT_DIM + col] = acc[i][j2][r] + bv;
      }
    }
  }
}

// ---- launch -----------------------------------------------------------------

extern "C" void kernel_launch(void* const* d_in, const int* in_sizes, int n_in,
                              void* d_out, int out_size, void* d_ws, size_t ws_size,
                              hipStream_t stream) {
  const float* x = (const float*)d_in[0];       // [4096][8192] fp32
  const int* row_idx = (const int*)d_in[1];     // [NNZ] int32
  const int* col_idx = (const int*)d_in[2];     // [NNZ] int32
  const float* weights = (const float*)d_in[3]; // [NNZ] fp32
  const float* bias = (const float*)d_in[4];    // [4096] fp32
  float* out = (float*)d_out;                   // [4096][4096] fp32

  // ws layout: W_bf16 [0,64M), x_bf16 [64M,128M).
  const size_t W_BF16_BYTES = (size_t)IN_DIM * OUT_DIM * 2;  // 64 MiB
  unsigned short* W_bf16 = (unsigned short*)d_ws;
  unsigned short* x_bf16 = (unsigned short*)((char*)d_ws + W_BF16_BYTES);

  static bool attr_set = false;
  if (!attr_set) {
    (void)hipFuncSetAttribute((const void*)gemm_kernel,
                              hipFuncAttributeMaxDynamicSharedMemorySize,
                              131072);
    attr_set = true;
  }

  // 1. zero W_bf16 + convert x -> bf16
  prep_kernel<<<PREP_BLOCKS, 256, 0, stream>>>((uint4*)W_bf16, x, x_bf16);

  // 2. scatter-add weights directly into bf16 W^T (CAS)
  scatter_kernel<<<SCAT_BLOCKS, 256, 0, stream>>>(
      (const int4*)row_idx, (const int4*)col_idx, (const float4*)weights,
      (unsigned int*)W_bf16);

  // 3. GEMM + bias (256^2 tile, 8 waves, XCD-region-swizzled grid of 256)
  gemm_kernel<<<dim3(256), dim3(512), 131072, stream>>>(x_bf16, W_bf16, bias, out);
}